// Round 1
// baseline (1124.942 us; speedup 1.0000x reference)
//
#include <hip/hip_runtime.h>
#include <stdint.h>

typedef unsigned short u16;
typedef unsigned int   u32;
typedef __bf16 bf16x8 __attribute__((ext_vector_type(8)));
typedef float  f32x4  __attribute__((ext_vector_type(4)));
typedef u16    u16x8  __attribute__((ext_vector_type(8)));
typedef u16    u16x4  __attribute__((ext_vector_type(4)));

// Problem dims
#define NB    4
#define NS    4096
#define NHID  2048
#define NHEAD 16
#define HDIM  128
#define MTOT  16384   // NB*NS

__device__ __forceinline__ u16 f2bf(float f) {
  u32 u = __builtin_bit_cast(u32, f);
  u = (u + 0x7fffu + ((u >> 16) & 1u)) >> 16;
  return (u16)u;
}
__device__ __forceinline__ float bf2f(u16 h) {
  return __builtin_bit_cast(float, ((u32)h) << 16);
}

// async global->LDS, 16B per lane. LDS dest must be linear: base + lane*16.
__device__ __forceinline__ void async_copy16(u16* lds_dst, const u16* g_src) {
  __builtin_amdgcn_global_load_lds(
      (__attribute__((address_space(1))) u32*)(const_cast<u16*>(g_src)),
      (__attribute__((address_space(3))) u32*)(lds_dst),
      16, 0, 0);
}

// ---------------------------------------------------------------------------
// Shared GEMM core: C(128x128) = A[128xK] * B^T where B given as BT[128xK].
// BK=32, 4 waves (2x2), each wave 64x64 = 4x4 frags of 16x16x32 bf16 MFMA.
// m97-verified structure: global_load_lds(16B) staging + 2 barriers per K-step.
// ---------------------------------------------------------------------------
__device__ __forceinline__ void gemm_core(const u16* A, int lda,
                                          const u16* B, int ldb,
                                          int K, f32x4 acc[4][4],
                                          u16* As, u16* Bs)
{
  const int tid  = threadIdx.x;
  const int lane = tid & 63;
  const int w    = tid >> 6;
  const int wr   = (w >> 1) << 6;
  const int wc   = (w & 1) << 6;
  const int lg   = lane >> 4;
  const int lr   = lane & 15;

#pragma unroll
  for (int m = 0; m < 4; ++m)
#pragma unroll
    for (int n = 0; n < 4; ++n) acc[m][n] = f32x4{0.f, 0.f, 0.f, 0.f};

  for (int k0 = 0; k0 < K; k0 += 32) {
    // stage A tile [128][32] and BT tile [128][32]; 16B per lane, 2 issues each
#pragma unroll
    for (int issue = 0; issue < 2; ++issue) {
      int c   = issue * 256 + tid;
      int row = c >> 2, cc = (c & 3) << 3;
      async_copy16(As + c * 8, A + (size_t)row * lda + k0 + cc);
    }
#pragma unroll
    for (int issue = 0; issue < 2; ++issue) {
      int c   = issue * 256 + tid;
      int row = c >> 2, cc = (c & 3) << 3;
      async_copy16(Bs + c * 8, B + (size_t)row * ldb + k0 + cc);
    }
    __syncthreads();  // compiler drains vmcnt(0) -> tiles ready

    bf16x8 af[4], bv[4];
#pragma unroll
    for (int m = 0; m < 4; ++m)
      af[m] = *(const bf16x8*)(As + ((wr + m * 16 + lr) << 5) + (lg << 3));
#pragma unroll
    for (int n = 0; n < 4; ++n)
      bv[n] = *(const bf16x8*)(Bs + ((wc + n * 16 + lr) << 5) + (lg << 3));

#pragma unroll
    for (int m = 0; m < 4; ++m)
#pragma unroll
      for (int n = 0; n < 4; ++n)
        acc[m][n] = __builtin_amdgcn_mfma_f32_16x16x32_bf16(af[m], bv[n], acc[m][n], 0, 0, 0);

    __syncthreads();  // protect tiles before next-iter overwrite
  }
}

// ---------------------------------------------------------------------------
// GEMM1: qkvg = x_bf16 [16384,2048] @ WTcat^T [8192,2048], +bias, sigmoid on g
// grid (128 mtiles, 64 ntiles)
// ---------------------------------------------------------------------------
__global__ __launch_bounds__(256) void k_gemm_qkvg(
    const u16* __restrict__ xb, const u16* __restrict__ WT,
    const float* __restrict__ bias,
    u16* __restrict__ q, u16* __restrict__ k, u16* __restrict__ v, u16* __restrict__ g)
{
  __shared__ u16 As[128 * 32];
  __shared__ u16 Bs[128 * 32];
  const int mt = blockIdx.x, nt = blockIdx.y;
  const size_t bm0 = (size_t)mt << 7;
  const int    bn0 = nt << 7;
  f32x4 acc[4][4];
  gemm_core(xb + bm0 * NHID, NHID, WT + (size_t)bn0 * NHID, NHID, NHID, acc, As, Bs);

  const int nblk = bn0 >> 11;          // 0=q 1=k 2=v 3=g (tile lies in one block)
  const int ocol0 = bn0 & 2047;
  u16* outp = (nblk == 0) ? q : (nblk == 1) ? k : (nblk == 2) ? v : g;
  const bool sig = (nblk == 3);

  const int tid = threadIdx.x, lane = tid & 63, w = tid >> 6;
  const int wr = (w >> 1) << 6, wc = (w & 1) << 6, lg = lane >> 4, lr = lane & 15;
#pragma unroll
  for (int m = 0; m < 4; ++m) {
#pragma unroll
    for (int n = 0; n < 4; ++n) {
      const int col = ocol0 + wc + n * 16 + lr;
      const float bia = bias[bn0 + wc + n * 16 + lr];
#pragma unroll
      for (int j = 0; j < 4; ++j) {
        const size_t row = bm0 + wr + m * 16 + lg * 4 + j;
        float val = acc[m][n][j] + bia;
        if (sig) val = 1.f / (1.f + __expf(-val));
        outp[row * NHID + col] = f2bf(val);
      }
    }
  }
}

// ---------------------------------------------------------------------------
// kv partial: C[e][d] = sum_{s chunk} vT[e][s]*kT[d][s]; grid (64 bh, 8 split)
// ---------------------------------------------------------------------------
__global__ __launch_bounds__(256) void k_gemm_kv(
    const u16* __restrict__ vT, const u16* __restrict__ kT, float* __restrict__ part)
{
  __shared__ u16 As[128 * 32];
  __shared__ u16 Bs[128 * 32];
  const int bh = blockIdx.x, sp = blockIdx.y;
  const u16* A = vT + (size_t)bh * (HDIM * NS) + sp * 512;
  const u16* Bt = kT + (size_t)bh * (HDIM * NS) + sp * 512;
  f32x4 acc[4][4];
  gemm_core(A, NS, Bt, NS, 512, acc, As, Bs);

  float* outp = part + ((size_t)sp * 64 + bh) * 16384;
  const int tid = threadIdx.x, lane = tid & 63, w = tid >> 6;
  const int wr = (w >> 1) << 6, wc = (w & 1) << 6, lg = lane >> 4, lr = lane & 15;
#pragma unroll
  for (int m = 0; m < 4; ++m)
#pragma unroll
    for (int n = 0; n < 4; ++n) {
      const int col = wc + n * 16 + lr;
#pragma unroll
      for (int j = 0; j < 4; ++j) {
        const int row = wr + m * 16 + lg * 4 + j;
        outp[row * 128 + col] = acc[m][n][j];
      }
    }
}

// ---------------------------------------------------------------------------
// attn = (q @ kv) * g ; A=q[bs0.., head cols], BT=kvT[bh] (=kv^T), K=128
// grid (32 stiles, 64 bh)
// ---------------------------------------------------------------------------
__global__ __launch_bounds__(256) void k_gemm_attn(
    const u16* __restrict__ q, const u16* __restrict__ kvT,
    const u16* __restrict__ g, u16* __restrict__ attn)
{
  __shared__ u16 As[128 * 32];
  __shared__ u16 Bs[128 * 32];
  const int st = blockIdx.x, bh = blockIdx.y;
  const int b = bh >> 4, h = bh & 15;
  const size_t bs0 = (size_t)b * NS + st * 128;
  f32x4 acc[4][4];
  gemm_core(q + bs0 * NHID + h * HDIM, NHID, kvT + (size_t)bh * 16384, HDIM, HDIM, acc, As, Bs);

  const int tid = threadIdx.x, lane = tid & 63, w = tid >> 6;
  const int wr = (w >> 1) << 6, wc = (w & 1) << 6, lg = lane >> 4, lr = lane & 15;
#pragma unroll
  for (int m = 0; m < 4; ++m)
#pragma unroll
    for (int n = 0; n < 4; ++n) {
      const int col = wc + n * 16 + lr;
#pragma unroll
      for (int j = 0; j < 4; ++j) {
        const int row = wr + m * 16 + lg * 4 + j;
        const size_t idx = (bs0 + row) * NHID + h * HDIM + col;
        attn[idx] = f2bf(acc[m][n][j] * bf2f(g[idx]));
      }
    }
}

// ---------------------------------------------------------------------------
// out = attn @ WoT^T + bo (fp32 out); grid (128 mtiles, 16 ntiles)
// ---------------------------------------------------------------------------
__global__ __launch_bounds__(256) void k_gemm_out(
    const u16* __restrict__ attn, const u16* __restrict__ WoT,
    const float* __restrict__ bo, float* __restrict__ out)
{
  __shared__ u16 As[128 * 32];
  __shared__ u16 Bs[128 * 32];
  const int mt = blockIdx.x, nt = blockIdx.y;
  const size_t bm0 = (size_t)mt << 7;
  const int    bn0 = nt << 7;
  f32x4 acc[4][4];
  gemm_core(attn + bm0 * NHID, NHID, WoT + (size_t)bn0 * NHID, NHID, NHID, acc, As, Bs);

  const int tid = threadIdx.x, lane = tid & 63, w = tid >> 6;
  const int wr = (w >> 1) << 6, wc = (w & 1) << 6, lg = lane >> 4, lr = lane & 15;
#pragma unroll
  for (int m = 0; m < 4; ++m)
#pragma unroll
    for (int n = 0; n < 4; ++n) {
      const int col = bn0 + wc + n * 16 + lr;
      const float bia = bo[col];
#pragma unroll
      for (int j = 0; j < 4; ++j) {
        const size_t row = bm0 + wr + m * 16 + lg * 4 + j;
        out[row * NHID + col] = acc[m][n][j] + bia;
      }
    }
}

// ---------------------------------------------------------------------------
// x fp32 -> bf16, 8 elems/thread; grid 16384 x 256
// ---------------------------------------------------------------------------
__global__ __launch_bounds__(256) void k_cvt_x(const float* __restrict__ x, u16* __restrict__ xb)
{
  const size_t i = (size_t)blockIdx.x * 256 + threadIdx.x;  // chunk of 8
  const float4* xf = (const float4*)x;
  float4 a = xf[2 * i];
  float4 b = xf[2 * i + 1];
  u16x8 o;
  o[0] = f2bf(a.x); o[1] = f2bf(a.y); o[2] = f2bf(a.z); o[3] = f2bf(a.w);
  o[4] = f2bf(b.x); o[5] = f2bf(b.y); o[6] = f2bf(b.z); o[7] = f2bf(b.w);
  ((u16x8*)xb)[i] = o;
}

// ---------------------------------------------------------------------------
// W [2048][2048] fp32 -> WT [2048][2048] bf16 with WT[n][k]=W[k][n]
// 64x64 LDS tiles; grid (32 ktiles, 32 ntiles)
// ---------------------------------------------------------------------------
__global__ __launch_bounds__(256) void k_cvt_w_t(const float* __restrict__ W, u16* __restrict__ WT)
{
  __shared__ u16 t[64][72];
  const int kt = blockIdx.x, nt = blockIdx.y;
  const int tid = threadIdx.x;
#pragma unroll
  for (int pass = 0; pass < 4; ++pass) {
    int c = pass * 256 + tid;            // 1024 chunks x 4 floats
    int r = c >> 4, cc = (c & 15) << 2;
    float4 vv = *(const float4*)(W + (size_t)(kt * 64 + r) * 2048 + nt * 64 + cc);
    u16x4 o;
    o[0] = f2bf(vv.x); o[1] = f2bf(vv.y); o[2] = f2bf(vv.z); o[3] = f2bf(vv.w);
    *(u16x4*)&t[r][cc] = o;
  }
  __syncthreads();
#pragma unroll
  for (int pass = 0; pass < 2; ++pass) {
    int c = pass * 256 + tid;            // 512 chunks x 8
    int rn = c >> 3, cs = (c & 7) << 3;
    u16x8 o;
#pragma unroll
    for (int j = 0; j < 8; ++j) o[j] = t[cs + j][rn];
    *(u16x8*)(WT + (size_t)(nt * 64 + rn) * 2048 + kt * 64 + cs) = o;
  }
}

// ---------------------------------------------------------------------------
// bf16 [B][S][NH*128] -> [bh][128][S] transpose; grid 8192 (64 st x 2 dt x 64 bh)
// ---------------------------------------------------------------------------
__global__ __launch_bounds__(256) void k_transpose_hd(const u16* __restrict__ src, u16* __restrict__ dst)
{
  __shared__ u16 t[64][72];
  const int blk = blockIdx.x;
  const int st = blk & 63;
  const int dt = (blk >> 6) & 1;
  const int bh = blk >> 7;
  const int b = bh >> 4, h = bh & 15;
  const int tid = threadIdx.x;
  const u16* sbase = src + ((size_t)b * NS + st * 64) * NHID + h * HDIM + dt * 64;
#pragma unroll
  for (int pass = 0; pass < 2; ++pass) {
    int c = pass * 256 + tid;
    int r = c >> 3, cc = (c & 7) << 3;
    u16x8 vv = *(const u16x8*)(sbase + (size_t)r * NHID + cc);
    *(u16x8*)&t[r][cc] = vv;
  }
  __syncthreads();
  u16* dbase = dst + ((size_t)bh * HDIM + dt * 64) * NS + st * 64;
#pragma unroll
  for (int pass = 0; pass < 2; ++pass) {
    int c = pass * 256 + tid;
    int rd = c >> 3, cs = (c & 7) << 3;
    u16x8 o;
#pragma unroll
    for (int j = 0; j < 8; ++j) o[j] = t[cs + j][rd];
    *(u16x8*)(dbase + (size_t)rd * NS + cs) = o;
  }
}

// ---------------------------------------------------------------------------
__global__ __launch_bounds__(256) void k_bias_cat(
    const float* __restrict__ bq, const float* __restrict__ bk,
    const float* __restrict__ bv, const float* __restrict__ bg, float* __restrict__ o)
{
  const int i = blockIdx.x * 256 + threadIdx.x;  // 8192
  const int blk = i >> 11;
  const float* s = (blk == 0) ? bq : (blk == 1) ? bk : (blk == 2) ? bv : bg;
  o[i] = s[i & 2047];
}

__global__ __launch_bounds__(256) void k_kv_reduce(const float* __restrict__ part, u16* __restrict__ kvT)
{
  const int i = blockIdx.x * 256 + threadIdx.x;  // 1,048,576
  float s = 0.f;
#pragma unroll
  for (int sp = 0; sp < 8; ++sp) s += part[(size_t)sp * 1048576 + i];
  kvT[i] = f2bf(s);
}

// ---------------------------------------------------------------------------
extern "C" void kernel_launch(void* const* d_in, const int* in_sizes, int n_in,
                              void* d_out, int out_size, void* d_ws, size_t ws_size,
                              hipStream_t stream)
{
  const float* x  = (const float*)d_in[0];
  const float* Wq = (const float*)d_in[1];
  const float* bq = (const float*)d_in[2];
  const float* Wk = (const float*)d_in[3];
  const float* bk = (const float*)d_in[4];
  const float* Wv = (const float*)d_in[5];
  const float* bv = (const float*)d_in[6];
  const float* Wg = (const float*)d_in[7];
  const float* bg = (const float*)d_in[8];
  const float* Wo = (const float*)d_in[9];
  const float* bo = (const float*)d_in[10];
  float* out = (float*)d_out;

  char* ws = (char*)d_ws;
  // workspace layout (bytes)
  u16*   xb   = (u16*)(ws + 0x00000000ULL);  // 64MB  x bf16
  u16*   WT   = (u16*)(ws + 0x04000000ULL);  // 32MB  [Wq|Wk|Wv|Wg]^T bf16
  u16*   WoT  = (u16*)(ws + 0x06000000ULL);  // 8MB
  float* bias = (float*)(ws + 0x06800000ULL);// 32KB
  u16*   q    = (u16*)(ws + 0x06900000ULL);  // 64MB
  u16*   kk   = (u16*)(ws + 0x0A900000ULL);  // 64MB
  u16*   vv   = (u16*)(ws + 0x0E900000ULL);  // 64MB
  u16*   gg   = (u16*)(ws + 0x12900000ULL);  // 64MB
  u16*   kvT  = (u16*)(ws + 0x16900000ULL);  // 2MB
  // aliases (producer/consumer disjoint across sequential launches)
  u16*   kT   = xb;          // xb dead after qkvg GEMM
  u16*   vT   = kk;          // k dead after its transpose
  float* part = (float*)WT;  // WTcat dead after qkvg GEMM (exactly 32MB)
  u16*   attn = vv;          // v dead after its transpose

  if (ws_size < 0x16B00000ULL) return;  // need ~381MB scratch

  k_cvt_x<<<16384, 256, 0, stream>>>(x, xb);
  k_cvt_w_t<<<dim3(32, 32), 256, 0, stream>>>(Wq, WT);
  k_cvt_w_t<<<dim3(32, 32), 256, 0, stream>>>(Wk, WT + (size_t)2048 * 2048);
  k_cvt_w_t<<<dim3(32, 32), 256, 0, stream>>>(Wv, WT + (size_t)2 * 2048 * 2048);
  k_cvt_w_t<<<dim3(32, 32), 256, 0, stream>>>(Wg, WT + (size_t)3 * 2048 * 2048);
  k_cvt_w_t<<<dim3(32, 32), 256, 0, stream>>>(Wo, WoT);
  k_bias_cat<<<32, 256, 0, stream>>>(bq, bk, bv, bg, bias);

  k_gemm_qkvg<<<dim3(128, 64), 256, 0, stream>>>(xb, WT, bias, q, kk, vv, gg);

  k_transpose_hd<<<8192, 256, 0, stream>>>(kk, kT);
  k_transpose_hd<<<8192, 256, 0, stream>>>(vv, vT);

  k_gemm_kv<<<dim3(64, 8), 256, 0, stream>>>(vT, kT, part);
  k_kv_reduce<<<4096, 256, 0, stream>>>(part, kvT);

  k_gemm_attn<<<dim3(32, 64), 256, 0, stream>>>(q, kvT, gg, attn);
  k_gemm_out<<<dim3(128, 16), 256, 0, stream>>>(attn, WoT, bo, out);
}

// Round 2
// 1083.616 us; speedup vs baseline: 1.0381x; 1.0381x over previous
//
#include <hip/hip_runtime.h>
#include <stdint.h>

typedef unsigned short u16;
typedef unsigned int   u32;
typedef __bf16 bf16x8 __attribute__((ext_vector_type(8)));
typedef float  f32x4  __attribute__((ext_vector_type(4)));
typedef u16    u16x8  __attribute__((ext_vector_type(8)));
typedef u16    u16x4  __attribute__((ext_vector_type(4)));

// Problem dims
#define NB    4
#define NS    4096
#define NHID  2048
#define NHEAD 16
#define HDIM  128
#define MTOT  16384   // NB*NS
#define KTILES 64     // 2048 / 32

__device__ __forceinline__ u16 f2bf(float f) {
  u32 u = __builtin_bit_cast(u32, f);
  u = (u + 0x7fffu + ((u >> 16) & 1u)) >> 16;
  return (u16)u;
}
__device__ __forceinline__ float bf2f(u16 h) {
  return __builtin_bit_cast(float, ((u32)h) << 16);
}

// async global->LDS, 16B per lane. HW dest = first-lane base + lane*16.
__device__ __forceinline__ void async_copy16(u16* lds_dst, const u16* g_src) {
  __builtin_amdgcn_global_load_lds(
      (__attribute__((address_space(1))) u32*)(const_cast<u16*>(g_src)),
      (__attribute__((address_space(3))) u32*)(lds_dst),
      16, 0, 0);
}

// ===========================================================================
// 256x256 tile GEMM core, BK=32, 8 waves (2M x 4N), 4-deep LDS ring,
// counted vmcnt (never drained in steady state), T2 swizzle, T5 setprio.
// A[256xK] row-major bf16 (lda=2048), B given transposed BT[256xK] (ldb=2048).
// LDS tiles [256][32] bf16; swizzle: byte ^= ((row&3)<<4)  (involution).
// Staged via pre-swizzled GLOBAL source (gload_lds dest must stay linear).
// ===========================================================================
__device__ __forceinline__ void stage256(const u16* __restrict__ A,
                                         const u16* __restrict__ B,
                                         u16* As, u16* Bs,
                                         int T, int w, int lane)
{
  const u16* Ak = A + T * 32;
  const u16* Bk = B + T * 32;
#pragma unroll
  for (int i = 0; i < 2; ++i) {
    const int u   = ((w * 2 + i) << 6) + lane;   // 16B-unit index in [0,1024)
    const int row = u >> 2;
    const int col = (((u & 3) ^ (row & 3)) << 3); // swizzled source column (elems)
    async_copy16(As + u * 8, Ak + (size_t)row * 2048 + col);
  }
#pragma unroll
  for (int i = 0; i < 2; ++i) {
    const int u   = ((w * 2 + i) << 6) + lane;
    const int row = u >> 2;
    const int col = (((u & 3) ^ (row & 3)) << 3);
    async_copy16(Bs + u * 8, Bk + (size_t)row * 2048 + col);
  }
}

template<int VM>
__device__ __forceinline__ void body256(const u16* Abuf, const u16* Bbuf,
                                        f32x4 (&acc)[8][4],
                                        int wr, int wc, int lg, int lr)
{
  // counted wait: everything except the VM newest loads has landed
  asm volatile("s_waitcnt vmcnt(%0)" :: "n"(VM) : "memory");
  __builtin_amdgcn_s_barrier();
  asm volatile("" ::: "memory");

  const int xr = ((lg ^ (lr & 3)) << 3);   // swizzled k-granule (row&3 == lr&3)
  bf16x8 aR[8], bR[4];
#pragma unroll
  for (int m = 0; m < 8; ++m)
    aR[m] = *(const bf16x8*)(Abuf + ((wr << 7) + (m << 4) + lr) * 32 + xr);
#pragma unroll
  for (int n = 0; n < 4; ++n)
    bR[n] = *(const bf16x8*)(Bbuf + ((wc << 6) + (n << 4) + lr) * 32 + xr);

  __builtin_amdgcn_s_setprio(1);
#pragma unroll
  for (int m = 0; m < 8; ++m)
#pragma unroll
    for (int n = 0; n < 4; ++n)
      acc[m][n] = __builtin_amdgcn_mfma_f32_16x16x32_bf16(aR[m], bR[n], acc[m][n], 0, 0, 0);
  __builtin_amdgcn_s_setprio(0);

  // all this iter's LDS reads must retire before anyone overwrites this buffer
  asm volatile("s_waitcnt lgkmcnt(0)" ::: "memory");
  __builtin_amdgcn_s_barrier();
  asm volatile("" ::: "memory");
}

__device__ __forceinline__ void gemm256(const u16* __restrict__ A,
                                        const u16* __restrict__ B,
                                        f32x4 (&acc)[8][4],
                                        u16 (*As)[8192], u16 (*Bs)[8192])
{
  const int tid = threadIdx.x, lane = tid & 63, w = tid >> 6;
  const int wr = w >> 2, wc = w & 3, lg = lane >> 4, lr = lane & 15;

#pragma unroll
  for (int m = 0; m < 8; ++m)
#pragma unroll
    for (int n = 0; n < 4; ++n) acc[m][n] = f32x4{0.f, 0.f, 0.f, 0.f};

  stage256(A, B, As[0], Bs[0], 0, w, lane);
  stage256(A, B, As[1], Bs[1], 1, w, lane);
  stage256(A, B, As[2], Bs[2], 2, w, lane);

  for (int t = 0; t + 3 < KTILES; ++t) {
    stage256(A, B, As[(t + 3) & 3], Bs[(t + 3) & 3], t + 3, w, lane);
    body256<12>(As[t & 3], Bs[t & 3], acc, wr, wc, lg, lr);
  }
  body256<8>(As[(KTILES - 3) & 3], Bs[(KTILES - 3) & 3], acc, wr, wc, lg, lr);
  body256<4>(As[(KTILES - 2) & 3], Bs[(KTILES - 2) & 3], acc, wr, wc, lg, lr);
  body256<0>(As[(KTILES - 1) & 3], Bs[(KTILES - 1) & 3], acc, wr, wc, lg, lr);
}

// ---------------------------------------------------------------------------
// GEMM1: qkvg = x_bf16 [16384,2048] @ WTcat^T [8192,2048], +bias, sigmoid on g
// grid: 2048 blocks (64 mt x 32 nt), 16x16 supergroups
// ---------------------------------------------------------------------------
__global__ __launch_bounds__(512, 2) void k_gemm_qkvg(
    const u16* __restrict__ xb, const u16* __restrict__ WT,
    const float* __restrict__ bias,
    u16* __restrict__ q, u16* __restrict__ k, u16* __restrict__ v, u16* __restrict__ g)
{
  __shared__ u16 As[4][8192];
  __shared__ u16 Bs[4][8192];
  const int bid = blockIdx.x;
  const int grp = bid >> 8, r = bid & 255;
  const int mt = ((grp & 3) << 4) + (r & 15);
  const int nt = ((grp >> 2) << 4) + (r >> 4);
  const size_t bm0 = (size_t)mt << 8;
  const int    bn0 = nt << 8;

  f32x4 acc[8][4];
  gemm256(xb + bm0 * NHID, WT + (size_t)bn0 * NHID, acc, As, Bs);

  const int nblk = bn0 >> 11;          // 0=q 1=k 2=v 3=g
  const int ocol0 = bn0 & 2047;
  u16* outp = (nblk == 0) ? q : (nblk == 1) ? k : (nblk == 2) ? v : g;
  const bool sig = (nblk == 3);

  const int tid = threadIdx.x, lane = tid & 63, w = tid >> 6;
  const int wr = w >> 2, wc = w & 3, lg = lane >> 4, lr = lane & 15;
#pragma unroll
  for (int m = 0; m < 8; ++m) {
#pragma unroll
    for (int n = 0; n < 4; ++n) {
      const int coln = (wc << 6) + (n << 4) + lr;
      const int col  = ocol0 + coln;
      const float bia = bias[bn0 + coln];
#pragma unroll
      for (int j = 0; j < 4; ++j) {
        const size_t row = bm0 + (wr << 7) + (m << 4) + (lg << 2) + j;
        float val = acc[m][n][j] + bia;
        if (sig) val = 1.f / (1.f + __expf(-val));
        outp[row * NHID + col] = f2bf(val);
      }
    }
  }
}

// ---------------------------------------------------------------------------
// out = attn @ WoT^T + bo (fp32 out); grid: 512 blocks (64 mt x 8 nt)
// ---------------------------------------------------------------------------
__global__ __launch_bounds__(512, 2) void k_gemm_out(
    const u16* __restrict__ attn, const u16* __restrict__ WoT,
    const float* __restrict__ bo, float* __restrict__ out)
{
  __shared__ u16 As[4][8192];
  __shared__ u16 Bs[4][8192];
  const int bid = blockIdx.x;
  const int grp = bid >> 7, r = bid & 127;
  const int mt = (grp << 4) + (r & 15);
  const int nt = r >> 4;
  const size_t bm0 = (size_t)mt << 8;
  const int    bn0 = nt << 8;

  f32x4 acc[8][4];
  gemm256(attn + bm0 * NHID, WoT + (size_t)bn0 * NHID, acc, As, Bs);

  const int tid = threadIdx.x, lane = tid & 63, w = tid >> 6;
  const int wr = w >> 2, wc = w & 3, lg = lane >> 4, lr = lane & 15;
#pragma unroll
  for (int m = 0; m < 8; ++m) {
#pragma unroll
    for (int n = 0; n < 4; ++n) {
      const int col = bn0 + (wc << 6) + (n << 4) + lr;
      const float bia = bo[col];
#pragma unroll
      for (int j = 0; j < 4; ++j) {
        const size_t row = bm0 + (wr << 7) + (m << 4) + (lg << 2) + j;
        out[row * NHID + col] = acc[m][n][j] + bia;
      }
    }
  }
}

// ===========================================================================
// Small 128x128 GEMM core (round-0 verified) for the tiny per-head GEMMs
// ===========================================================================
__device__ __forceinline__ void gemm_core(const u16* A, int lda,
                                          const u16* B, int ldb,
                                          int K, f32x4 acc[4][4],
                                          u16* As, u16* Bs)
{
  const int tid  = threadIdx.x;
  const int lane = tid & 63;
  const int w    = tid >> 6;
  const int wr   = (w >> 1) << 6;
  const int wc   = (w & 1) << 6;
  const int lg   = lane >> 4;
  const int lr   = lane & 15;

#pragma unroll
  for (int m = 0; m < 4; ++m)
#pragma unroll
    for (int n = 0; n < 4; ++n) acc[m][n] = f32x4{0.f, 0.f, 0.f, 0.f};

  for (int k0 = 0; k0 < K; k0 += 32) {
#pragma unroll
    for (int issue = 0; issue < 2; ++issue) {
      int c   = issue * 256 + tid;
      int row = c >> 2, cc = (c & 3) << 3;
      async_copy16(As + c * 8, A + (size_t)row * lda + k0 + cc);
    }
#pragma unroll
    for (int issue = 0; issue < 2; ++issue) {
      int c   = issue * 256 + tid;
      int row = c >> 2, cc = (c & 3) << 3;
      async_copy16(Bs + c * 8, B + (size_t)row * ldb + k0 + cc);
    }
    __syncthreads();

    bf16x8 af[4], bv[4];
#pragma unroll
    for (int m = 0; m < 4; ++m)
      af[m] = *(const bf16x8*)(As + ((wr + m * 16 + lr) << 5) + (lg << 3));
#pragma unroll
    for (int n = 0; n < 4; ++n)
      bv[n] = *(const bf16x8*)(Bs + ((wc + n * 16 + lr) << 5) + (lg << 3));

#pragma unroll
    for (int m = 0; m < 4; ++m)
#pragma unroll
      for (int n = 0; n < 4; ++n)
        acc[m][n] = __builtin_amdgcn_mfma_f32_16x16x32_bf16(af[m], bv[n], acc[m][n], 0, 0, 0);

    __syncthreads();
  }
}

// ---------------------------------------------------------------------------
// kv partial: C[e][d] = sum_{s chunk} vT[e][s]*kT[d][s]; grid (64 bh, 8 split)
// ---------------------------------------------------------------------------
__global__ __launch_bounds__(256) void k_gemm_kv(
    const u16* __restrict__ vT, const u16* __restrict__ kT, float* __restrict__ part)
{
  __shared__ u16 As[128 * 32];
  __shared__ u16 Bs[128 * 32];
  const int bh = blockIdx.x, sp = blockIdx.y;
  const u16* A  = vT + (size_t)bh * (HDIM * NS) + sp * 512;
  const u16* Bt = kT + (size_t)bh * (HDIM * NS) + sp * 512;
  f32x4 acc[4][4];
  gemm_core(A, NS, Bt, NS, 512, acc, As, Bs);

  float* outp = part + ((size_t)sp * 64 + bh) * 16384;
  const int tid = threadIdx.x, lane = tid & 63, w = tid >> 6;
  const int wr = (w >> 1) << 6, wc = (w & 1) << 6, lg = lane >> 4, lr = lane & 15;
#pragma unroll
  for (int m = 0; m < 4; ++m)
#pragma unroll
    for (int n = 0; n < 4; ++n) {
      const int col = wc + n * 16 + lr;
#pragma unroll
      for (int j = 0; j < 4; ++j) {
        const int row = wr + m * 16 + lg * 4 + j;
        outp[row * 128 + col] = acc[m][n][j];
      }
    }
}

// ---------------------------------------------------------------------------
// attn = (q @ kv) * g ; grid (32 stiles, 64 bh)
// ---------------------------------------------------------------------------
__global__ __launch_bounds__(256) void k_gemm_attn(
    const u16* __restrict__ q, const u16* __restrict__ kvT,
    const u16* __restrict__ g, u16* __restrict__ attn)
{
  __shared__ u16 As[128 * 32];
  __shared__ u16 Bs[128 * 32];
  const int st = blockIdx.x, bh = blockIdx.y;
  const int b = bh >> 4, h = bh & 15;
  const size_t bs0 = (size_t)b * NS + st * 128;
  f32x4 acc[4][4];
  gemm_core(q + bs0 * NHID + h * HDIM, NHID, kvT + (size_t)bh * 16384, HDIM, HDIM, acc, As, Bs);

  const int tid = threadIdx.x, lane = tid & 63, w = tid >> 6;
  const int wr = (w >> 1) << 6, wc = (w & 1) << 6, lg = lane >> 4, lr = lane & 15;
#pragma unroll
  for (int m = 0; m < 4; ++m)
#pragma unroll
    for (int n = 0; n < 4; ++n) {
      const int col = wc + n * 16 + lr;
#pragma unroll
      for (int j = 0; j < 4; ++j) {
        const int row = wr + m * 16 + lg * 4 + j;
        const size_t idx = (bs0 + row) * NHID + h * HDIM + col;
        attn[idx] = f2bf(acc[m][n][j] * bf2f(g[idx]));
      }
    }
}

// ---------------------------------------------------------------------------
// x fp32 -> bf16
// ---------------------------------------------------------------------------
__global__ __launch_bounds__(256) void k_cvt_x(const float* __restrict__ x, u16* __restrict__ xb)
{
  const size_t i = (size_t)blockIdx.x * 256 + threadIdx.x;
  const float4* xf = (const float4*)x;
  float4 a = xf[2 * i];
  float4 b = xf[2 * i + 1];
  u16x8 o;
  o[0] = f2bf(a.x); o[1] = f2bf(a.y); o[2] = f2bf(a.z); o[3] = f2bf(a.w);
  o[4] = f2bf(b.x); o[5] = f2bf(b.y); o[6] = f2bf(b.z); o[7] = f2bf(b.w);
  ((u16x8*)xb)[i] = o;
}

// ---------------------------------------------------------------------------
// W [2048][2048] fp32 -> WT bf16 transposed
// ---------------------------------------------------------------------------
__global__ __launch_bounds__(256) void k_cvt_w_t(const float* __restrict__ W, u16* __restrict__ WT)
{
  __shared__ u16 t[64][72];
  const int kt = blockIdx.x, nt = blockIdx.y;
  const int tid = threadIdx.x;
#pragma unroll
  for (int pass = 0; pass < 4; ++pass) {
    int c = pass * 256 + tid;
    int r = c >> 4, cc = (c & 15) << 2;
    float4 vv = *(const float4*)(W + (size_t)(kt * 64 + r) * 2048 + nt * 64 + cc);
    u16x4 o;
    o[0] = f2bf(vv.x); o[1] = f2bf(vv.y); o[2] = f2bf(vv.z); o[3] = f2bf(vv.w);
    *(u16x4*)&t[r][cc] = o;
  }
  __syncthreads();
#pragma unroll
  for (int pass = 0; pass < 2; ++pass) {
    int c = pass * 256 + tid;
    int rn = c >> 3, cs = (c & 7) << 3;
    u16x8 o;
#pragma unroll
    for (int j = 0; j < 8; ++j) o[j] = t[cs + j][rn];
    *(u16x8*)(WT + (size_t)(nt * 64 + rn) * 2048 + kt * 64 + cs) = o;
  }
}

// ---------------------------------------------------------------------------
// bf16 [B][S][NH*128] -> [bh][128][S] transpose
// ---------------------------------------------------------------------------
__global__ __launch_bounds__(256) void k_transpose_hd(const u16* __restrict__ src, u16* __restrict__ dst)
{
  __shared__ u16 t[64][72];
  const int blk = blockIdx.x;
  const int st = blk & 63;
  const int dt = (blk >> 6) & 1;
  const int bh = blk >> 7;
  const int b = bh >> 4, h = bh & 15;
  const int tid = threadIdx.x;
  const u16* sbase = src + ((size_t)b * NS + st * 64) * NHID + h * HDIM + dt * 64;
#pragma unroll
  for (int pass = 0; pass < 2; ++pass) {
    int c = pass * 256 + tid;
    int r = c >> 3, cc = (c & 7) << 3;
    u16x8 vv = *(const u16x8*)(sbase + (size_t)r * NHID + cc);
    *(u16x8*)&t[r][cc] = vv;
  }
  __syncthreads();
  u16* dbase = dst + ((size_t)bh * HDIM + dt * 64) * NS + st * 64;
#pragma unroll
  for (int pass = 0; pass < 2; ++pass) {
    int c = pass * 256 + tid;
    int rd = c >> 3, cs = (c & 7) << 3;
    u16x8 o;
#pragma unroll
    for (int j = 0; j < 8; ++j) o[j] = t[cs + j][rd];
    *(u16x8*)(dbase + (size_t)rd * NS + cs) = o;
  }
}

// ---------------------------------------------------------------------------
__global__ __launch_bounds__(256) void k_bias_cat(
    const float* __restrict__ bq, const float* __restrict__ bk,
    const float* __restrict__ bv, const float* __restrict__ bg, float* __restrict__ o)
{
  const int i = blockIdx.x * 256 + threadIdx.x;  // 8192
  const int blk = i >> 11;
  const float* s = (blk == 0) ? bq : (blk == 1) ? bk : (blk == 2) ? bv : bg;
  o[i] = s[i & 2047];
}

__global__ __launch_bounds__(256) void k_kv_reduce(const float* __restrict__ part, u16* __restrict__ kvT)
{
  const int i = blockIdx.x * 256 + threadIdx.x;  // 1,048,576
  float s = 0.f;
#pragma unroll
  for (int sp = 0; sp < 8; ++sp) s += part[(size_t)sp * 1048576 + i];
  kvT[i] = f2bf(s);
}

// ---------------------------------------------------------------------------
extern "C" void kernel_launch(void* const* d_in, const int* in_sizes, int n_in,
                              void* d_out, int out_size, void* d_ws, size_t ws_size,
                              hipStream_t stream)
{
  const float* x  = (const float*)d_in[0];
  const float* Wq = (const float*)d_in[1];
  const float* bq = (const float*)d_in[2];
  const float* Wk = (const float*)d_in[3];
  const float* bk = (const float*)d_in[4];
  const float* Wv = (const float*)d_in[5];
  const float* bv = (const float*)d_in[6];
  const float* Wg = (const float*)d_in[7];
  const float* bg = (const float*)d_in[8];
  const float* Wo = (const float*)d_in[9];
  const float* bo = (const float*)d_in[10];
  float* out = (float*)d_out;

  char* ws = (char*)d_ws;
  u16*   xb   = (u16*)(ws + 0x00000000ULL);  // 64MB
  u16*   WT   = (u16*)(ws + 0x04000000ULL);  // 32MB  [Wq|Wk|Wv|Wg]^T bf16
  u16*   WoT  = (u16*)(ws + 0x06000000ULL);  // 8MB
  float* bias = (float*)(ws + 0x06800000ULL);// 32KB
  u16*   q    = (u16*)(ws + 0x06900000ULL);  // 64MB
  u16*   kk   = (u16*)(ws + 0x0A900000ULL);  // 64MB
  u16*   vv   = (u16*)(ws + 0x0E900000ULL);  // 64MB
  u16*   gg   = (u16*)(ws + 0x12900000ULL);  // 64MB
  u16*   kvT  = (u16*)(ws + 0x16900000ULL);  // 2MB
  // aliases (producer/consumer disjoint across sequential launches)
  u16*   kT   = xb;
  u16*   vT   = kk;
  float* part = (float*)WT;
  u16*   attn = vv;

  if (ws_size < 0x16B00000ULL) return;

  k_cvt_x<<<16384, 256, 0, stream>>>(x, xb);
  k_cvt_w_t<<<dim3(32, 32), 256, 0, stream>>>(Wq, WT);
  k_cvt_w_t<<<dim3(32, 32), 256, 0, stream>>>(Wk, WT + (size_t)2048 * 2048);
  k_cvt_w_t<<<dim3(32, 32), 256, 0, stream>>>(Wv, WT + (size_t)2 * 2048 * 2048);
  k_cvt_w_t<<<dim3(32, 32), 256, 0, stream>>>(Wg, WT + (size_t)3 * 2048 * 2048);
  k_cvt_w_t<<<dim3(32, 32), 256, 0, stream>>>(Wo, WoT);
  k_bias_cat<<<32, 256, 0, stream>>>(bq, bk, bv, bg, bias);

  k_gemm_qkvg<<<2048, 512, 0, stream>>>(xb, WT, bias, q, kk, vv, gg);

  k_transpose_hd<<<8192, 256, 0, stream>>>(kk, kT);
  k_transpose_hd<<<8192, 256, 0, stream>>>(vv, vT);

  k_gemm_kv<<<dim3(64, 8), 256, 0, stream>>>(vT, kT, part);
  k_kv_reduce<<<4096, 256, 0, stream>>>(part, kvT);

  k_gemm_attn<<<dim3(32, 64), 256, 0, stream>>>(q, kvT, gg, attn);
  k_gemm_out<<<512, 512, 0, stream>>>(attn, WoT, bo, out);
}

// Round 3
// 837.051 us; speedup vs baseline: 1.3439x; 1.2946x over previous
//
#include <hip/hip_runtime.h>
#include <stdint.h>

typedef unsigned short u16;
typedef unsigned int   u32;
typedef __bf16 bf16x8 __attribute__((ext_vector_type(8)));
typedef float  f32x4  __attribute__((ext_vector_type(4)));
typedef u16    u16x8  __attribute__((ext_vector_type(8)));
typedef u16    u16x4  __attribute__((ext_vector_type(4)));

// Problem dims
#define NB    4
#define NS    4096
#define NHID  2048
#define NHEAD 16
#define HDIM  128
#define KSTEPS 64     // 2048 / 32

__device__ __forceinline__ u16 f2bf(float f) {
  u32 u = __builtin_bit_cast(u32, f);
  u = (u + 0x7fffu + ((u >> 16) & 1u)) >> 16;
  return (u16)u;
}
__device__ __forceinline__ float bf2f(u16 h) {
  return __builtin_bit_cast(float, ((u32)h) << 16);
}

// async global->LDS, 16B per lane. HW dest = first-lane base + lane*16 (linear).
__device__ __forceinline__ void async_copy16(u16* lds_dst, const u16* g_src) {
  __builtin_amdgcn_global_load_lds(
      (__attribute__((address_space(1))) u32*)(const_cast<u16*>(g_src)),
      (__attribute__((address_space(3))) u32*)(lds_dst),
      16, 0, 0);
}

// ===========================================================================
// 256x256 tile GEMM core, BK=32, 8 waves (2M x 4N), per-wave 128x64 output.
// 4-deep LDS ring (4 x 16KB x 2 = 128 KiB), counted vmcnt(8) in steady state.
// Swizzle: 16B-slot ^= (row>>1)&3  -> each ds_read_b128 spreads across all
// 32 banks at the 8x floor (2-way in-phase = free). Staged via pre-swizzled
// GLOBAL source (global_load_lds dest must stay linear).
// Body is compiler-scheduled (fine lgkmcnt interleave, m97-style); explicit
// waits only at ring boundaries.
// A[256xK] row-major bf16 (lda=2048), B transposed BT[256xK] (ldb=2048).
// SWAP=true computes with operands swapped: lane holds C[row=m*16+lr]
// [col=n*16+lg*4+j] -> contiguous-column vector stores.
// ===========================================================================
__device__ __forceinline__ void stage32(const u16* __restrict__ A,
                                        const u16* __restrict__ B,
                                        u16* As, u16* Bs, int kt, int tid)
{
  const u16* Ak = A + kt * 32;
  const u16* Bk = B + kt * 32;
#pragma unroll
  for (int i = 0; i < 2; ++i) {
    const int u = (i << 9) + tid;            // 16B unit in [0,1024)
    const int r = u >> 2;                    // tile row
    const int c = (((u & 3) ^ ((r >> 1) & 3)) << 3);  // inverse-swizzled src col
    async_copy16(As + u * 8, Ak + (size_t)r * 2048 + c);
  }
#pragma unroll
  for (int i = 0; i < 2; ++i) {
    const int u = (i << 9) + tid;
    const int r = u >> 2;
    const int c = (((u & 3) ^ ((r >> 1) & 3)) << 3);
    async_copy16(Bs + u * 8, Bk + (size_t)r * 2048 + c);
  }
}

template<int VM, bool STG, bool SWAP>
__device__ __forceinline__ void kstep(const u16* Ab, const u16* Bb,
                                      u16* Asg, u16* Bsg,
                                      const u16* __restrict__ A,
                                      const u16* __restrict__ B,
                                      int kt_stage, f32x4 (&acc)[8][4],
                                      int tid, int wr, int wc, int lr, int slot)
{
  __builtin_amdgcn_sched_barrier(0);
  asm volatile("s_waitcnt vmcnt(%0)" :: "n"(VM) : "memory");
  __builtin_amdgcn_s_barrier();
  __builtin_amdgcn_sched_barrier(0);

  if (STG) stage32(A, B, Asg, Bsg, kt_stage, tid);

  bf16x8 aR[8], bR[4];
#pragma unroll
  for (int m = 0; m < 8; ++m)
    aR[m] = *(const bf16x8*)(Ab + ((wr << 7) + (m << 4) + lr) * 32 + slot);
#pragma unroll
  for (int n = 0; n < 4; ++n)
    bR[n] = *(const bf16x8*)(Bb + ((wc << 6) + (n << 4) + lr) * 32 + slot);

  __builtin_amdgcn_s_setprio(1);
#pragma unroll
  for (int m = 0; m < 8; ++m)
#pragma unroll
    for (int n = 0; n < 4; ++n) {
      if (SWAP)
        acc[m][n] = __builtin_amdgcn_mfma_f32_16x16x32_bf16(bR[n], aR[m], acc[m][n], 0, 0, 0);
      else
        acc[m][n] = __builtin_amdgcn_mfma_f32_16x16x32_bf16(aR[m], bR[n], acc[m][n], 0, 0, 0);
    }
  __builtin_amdgcn_s_setprio(0);

  // reads of this buffer retired before the next boundary barrier
  asm volatile("s_waitcnt lgkmcnt(0)" ::: "memory");
  __builtin_amdgcn_sched_barrier(0);
}

template<bool SWAP>
__device__ __forceinline__ void gemm256(const u16* __restrict__ A,
                                        const u16* __restrict__ B,
                                        f32x4 (&acc)[8][4],
                                        u16 (*As)[8192], u16 (*Bs)[8192])
{
  const int tid = threadIdx.x, lane = tid & 63, w = tid >> 6;
  const int wr = w >> 2, wc = w & 3, lg = lane >> 4, lr = lane & 15;
  const int slot = ((lg ^ ((lr >> 1) & 3)) << 3);   // swizzled granule (elems)

#pragma unroll
  for (int m = 0; m < 8; ++m)
#pragma unroll
    for (int n = 0; n < 4; ++n) acc[m][n] = f32x4{0.f, 0.f, 0.f, 0.f};

  // prologue: 3 batches in flight (4 loads/thread each)
  stage32(A, B, As[0], Bs[0], 0, tid);
  stage32(A, B, As[1], Bs[1], 1, tid);
  stage32(A, B, As[2], Bs[2], 2, tid);

#pragma unroll 1
  for (int t = 0; t < KSTEPS - 4; t += 4) {
    kstep<8, true, SWAP>(As[0], Bs[0], As[3], Bs[3], A, B, t + 3, acc, tid, wr, wc, lr, slot);
    kstep<8, true, SWAP>(As[1], Bs[1], As[0], Bs[0], A, B, t + 4, acc, tid, wr, wc, lr, slot);
    kstep<8, true, SWAP>(As[2], Bs[2], As[1], Bs[1], A, B, t + 5, acc, tid, wr, wc, lr, slot);
    kstep<8, true, SWAP>(As[3], Bs[3], As[2], Bs[2], A, B, t + 6, acc, tid, wr, wc, lr, slot);
  }
  // t = 60..63 tail (KSTEPS=64): stage 63 at t=60, then drain 8 -> 4 -> 0
  kstep<8, true,  SWAP>(As[0], Bs[0], As[3], Bs[3], A, B, 63, acc, tid, wr, wc, lr, slot);
  kstep<8, false, SWAP>(As[1], Bs[1], nullptr, nullptr, A, B, 0, acc, tid, wr, wc, lr, slot);
  kstep<4, false, SWAP>(As[2], Bs[2], nullptr, nullptr, A, B, 0, acc, tid, wr, wc, lr, slot);
  kstep<0, false, SWAP>(As[3], Bs[3], nullptr, nullptr, A, B, 0, acc, tid, wr, wc, lr, slot);
}

// ---------------------------------------------------------------------------
// GEMM1: qkvg = x_bf16 [16384,2048] @ WTcat^T [8192,2048], +bias.
// q,g (swapped-C) -> [s][2048] with 8B vector stores (sigmoid on g);
// k,v (normal-C)  -> written DIRECTLY transposed [bh][d][s], 8B vector stores.
// grid: 2048 blocks (64 mt x 32 nt), 16x16 supergroups for L2.
// ---------------------------------------------------------------------------
__global__ __launch_bounds__(512, 2) void k_gemm_qkvg(
    const u16* __restrict__ xb, const u16* __restrict__ WT,
    const float* __restrict__ bias,
    u16* __restrict__ q, u16* __restrict__ kT, u16* __restrict__ vT,
    u16* __restrict__ g)
{
  __shared__ u16 As[4][8192];
  __shared__ u16 Bs[4][8192];
  const int bid = blockIdx.x;
  const int grp = bid >> 8, r = bid & 255;
  const int mt = ((grp & 3) << 4) + (r & 15);
  const int nt = ((grp >> 2) << 4) + (r >> 4);
  const size_t bm0 = (size_t)mt << 8;
  const int    bn0 = nt << 8;
  const int nblk = bn0 >> 11;          // 0=q 1=k 2=v 3=g
  const int ocol0 = bn0 & 2047;

  const int tid = threadIdx.x, lane = tid & 63, w = tid >> 6;
  const int wr = w >> 2, wc = w & 3, lg = lane >> 4, lr = lane & 15;

  f32x4 acc[8][4];
  const u16* Ap = xb + bm0 * NHID;
  const u16* Bp = WT + (size_t)bn0 * NHID;

  if (nblk == 0 || nblk == 3) {
    // ---- q / g: swapped-C, vector stores along columns ----
    gemm256<true>(Ap, Bp, acc, As, Bs);
    u16* outp = (nblk == 0) ? q : g;
    const bool sig = (nblk == 3);
#pragma unroll
    for (int m = 0; m < 8; ++m) {
      const size_t row = bm0 + (wr << 7) + (m << 4) + lr;
#pragma unroll
      for (int n = 0; n < 4; ++n) {
        const int colb = (wc << 6) + (n << 4) + (lg << 2);
        const float* bp = bias + bn0 + colb;
        u16x4 o;
#pragma unroll
        for (int j = 0; j < 4; ++j) {
          float val = acc[m][n][j] + bp[j];
          if (sig) val = 1.f / (1.f + __expf(-val));
          o[j] = f2bf(val);
        }
        *(u16x4*)(outp + row * NHID + ocol0 + colb) = o;
      }
    }
  } else {
    // ---- k / v: normal-C, direct transposed store [bh][d][s] ----
    gemm256<false>(Ap, Bp, acc, As, Bs);
    u16* outp = (nblk == 1) ? kT : vT;
    const int b = (int)(bm0 >> 12);
    const int srow0 = (int)(bm0 & 4095) + (wr << 7) + (lg << 2);
#pragma unroll
    for (int m = 0; m < 8; ++m) {
      const int srow = srow0 + (m << 4);
#pragma unroll
      for (int n = 0; n < 4; ++n) {
        const int cg = ocol0 + (wc << 6) + (n << 4) + lr;  // col in [0,2048)
        const int h = cg >> 7, d = cg & 127;
        const float bia = bias[bn0 + (wc << 6) + (n << 4) + lr];
        u16x4 o;
#pragma unroll
        for (int j = 0; j < 4; ++j) o[j] = f2bf(acc[m][n][j] + bia);
        *(u16x4*)(outp + (((size_t)(b * NHEAD + h) * HDIM + d) << 12) + srow) = o;
      }
    }
  }
}

// ---------------------------------------------------------------------------
// out = attn @ WoT^T + bo (fp32, swapped-C -> float4 stores)
// grid: 512 blocks (64 mt x 8 nt), 16x8 supergroups
// ---------------------------------------------------------------------------
__global__ __launch_bounds__(512, 2) void k_gemm_out(
    const u16* __restrict__ attn, const u16* __restrict__ WoT,
    const float* __restrict__ bo, float* __restrict__ out)
{
  __shared__ u16 As[4][8192];
  __shared__ u16 Bs[4][8192];
  const int bid = blockIdx.x;
  const int grp = bid >> 7, rr = bid & 127;
  const int mt = (grp << 4) + (rr & 15);
  const int nt = rr >> 4;
  const size_t bm0 = (size_t)mt << 8;
  const int    bn0 = nt << 8;

  const int tid = threadIdx.x, lane = tid & 63, w = tid >> 6;
  const int wr = w >> 2, wc = w & 3, lg = lane >> 4, lr = lane & 15;

  f32x4 acc[8][4];
  gemm256<true>(attn + bm0 * NHID, WoT + (size_t)bn0 * NHID, acc, As, Bs);

#pragma unroll
  for (int m = 0; m < 8; ++m) {
    const size_t row = bm0 + (wr << 7) + (m << 4) + lr;
#pragma unroll
    for (int n = 0; n < 4; ++n) {
      const int colb = bn0 + (wc << 6) + (n << 4) + (lg << 2);
      f32x4 o;
#pragma unroll
      for (int j = 0; j < 4; ++j) o[j] = acc[m][n][j] + bo[colb + j];
      *(f32x4*)(out + row * NHID + colb) = o;
    }
  }
}

// ===========================================================================
// Small 128x128 GEMM core (round-0 verified) for the tiny per-head GEMMs
// ===========================================================================
__device__ __forceinline__ void gemm_core(const u16* A, int lda,
                                          const u16* B, int ldb,
                                          int K, f32x4 acc[4][4],
                                          u16* As, u16* Bs)
{
  const int tid  = threadIdx.x;
  const int lane = tid & 63;
  const int w    = tid >> 6;
  const int wr   = (w >> 1) << 6;
  const int wc   = (w & 1) << 6;
  const int lg   = lane >> 4;
  const int lr   = lane & 15;

#pragma unroll
  for (int m = 0; m < 4; ++m)
#pragma unroll
    for (int n = 0; n < 4; ++n) acc[m][n] = f32x4{0.f, 0.f, 0.f, 0.f};

  for (int k0 = 0; k0 < K; k0 += 32) {
#pragma unroll
    for (int issue = 0; issue < 2; ++issue) {
      int c   = issue * 256 + tid;
      int row = c >> 2, cc = (c & 3) << 3;
      async_copy16(As + c * 8, A + (size_t)row * lda + k0 + cc);
    }
#pragma unroll
    for (int issue = 0; issue < 2; ++issue) {
      int c   = issue * 256 + tid;
      int row = c >> 2, cc = (c & 3) << 3;
      async_copy16(Bs + c * 8, B + (size_t)row * ldb + k0 + cc);
    }
    __syncthreads();

    bf16x8 af[4], bv[4];
#pragma unroll
    for (int m = 0; m < 4; ++m)
      af[m] = *(const bf16x8*)(As + ((wr + m * 16 + lr) << 5) + (lg << 3));
#pragma unroll
    for (int n = 0; n < 4; ++n)
      bv[n] = *(const bf16x8*)(Bs + ((wc + n * 16 + lr) << 5) + (lg << 3));

#pragma unroll
    for (int m = 0; m < 4; ++m)
#pragma unroll
      for (int n = 0; n < 4; ++n)
        acc[m][n] = __builtin_amdgcn_mfma_f32_16x16x32_bf16(af[m], bv[n], acc[m][n], 0, 0, 0);

    __syncthreads();
  }
}

// ---------------------------------------------------------------------------
// kv partial: C[e][d] = sum_{s chunk} vT[e][s]*kT[d][s]; grid (64 bh, 8 split)
// ---------------------------------------------------------------------------
__global__ __launch_bounds__(256) void k_gemm_kv(
    const u16* __restrict__ vT, const u16* __restrict__ kT, float* __restrict__ part)
{
  __shared__ u16 As[128 * 32];
  __shared__ u16 Bs[128 * 32];
  const int bh = blockIdx.x, sp = blockIdx.y;
  const u16* A  = vT + (size_t)bh * (HDIM * NS) + sp * 512;
  const u16* Bt = kT + (size_t)bh * (HDIM * NS) + sp * 512;
  f32x4 acc[4][4];
  gemm_core(A, NS, Bt, NS, 512, acc, As, Bs);

  float* outp = part + ((size_t)sp * 64 + bh) * 16384;
  const int tid = threadIdx.x, lane = tid & 63, w = tid >> 6;
  const int wr = (w >> 1) << 6, wc = (w & 1) << 6, lg = lane >> 4, lr = lane & 15;
#pragma unroll
  for (int m = 0; m < 4; ++m)
#pragma unroll
    for (int n = 0; n < 4; ++n) {
      const int col = wc + n * 16 + lr;
#pragma unroll
      for (int j = 0; j < 4; ++j) {
        const int row = wr + m * 16 + lg * 4 + j;
        outp[row * 128 + col] = acc[m][n][j];
      }
    }
}

// ---------------------------------------------------------------------------
// attn = (q @ kv) * g ; grid (32 stiles, 64 bh)
// ---------------------------------------------------------------------------
__global__ __launch_bounds__(256) void k_gemm_attn(
    const u16* __restrict__ q, const u16* __restrict__ kvT,
    const u16* __restrict__ g, u16* __restrict__ attn)
{
  __shared__ u16 As[128 * 32];
  __shared__ u16 Bs[128 * 32];
  const int st = blockIdx.x, bh = blockIdx.y;
  const int b = bh >> 4, h = bh & 15;
  const size_t bs0 = (size_t)b * NS + st * 128;
  f32x4 acc[4][4];
  gemm_core(q + bs0 * NHID + h * HDIM, NHID, kvT + (size_t)bh * 16384, HDIM, HDIM, acc, As, Bs);

  const int tid = threadIdx.x, lane = tid & 63, w = tid >> 6;
  const int wr = (w >> 1) << 6, wc = (w & 1) << 6, lg = lane >> 4, lr = lane & 15;
#pragma unroll
  for (int m = 0; m < 4; ++m)
#pragma unroll
    for (int n = 0; n < 4; ++n) {
      const int col = wc + n * 16 + lr;
#pragma unroll
      for (int j = 0; j < 4; ++j) {
        const int row = wr + m * 16 + lg * 4 + j;
        const size_t idx = (bs0 + row) * NHID + h * HDIM + col;
        attn[idx] = f2bf(acc[m][n][j] * bf2f(g[idx]));
      }
    }
}

// ---------------------------------------------------------------------------
// x fp32 -> bf16
// ---------------------------------------------------------------------------
__global__ __launch_bounds__(256) void k_cvt_x(const float* __restrict__ x, u16* __restrict__ xb)
{
  const size_t i = (size_t)blockIdx.x * 256 + threadIdx.x;
  const float4* xf = (const float4*)x;
  float4 a = xf[2 * i];
  float4 b = xf[2 * i + 1];
  u16x8 o;
  o[0] = f2bf(a.x); o[1] = f2bf(a.y); o[2] = f2bf(a.z); o[3] = f2bf(a.w);
  o[4] = f2bf(b.x); o[5] = f2bf(b.y); o[6] = f2bf(b.z); o[7] = f2bf(b.w);
  ((u16x8*)xb)[i] = o;
}

// ---------------------------------------------------------------------------
// W [2048][2048] fp32 -> WT bf16 transposed
// ---------------------------------------------------------------------------
__global__ __launch_bounds__(256) void k_cvt_w_t(const float* __restrict__ W, u16* __restrict__ WT)
{
  __shared__ u16 t[64][72];
  const int kt = blockIdx.x, nt = blockIdx.y;
  const int tid = threadIdx.x;
#pragma unroll
  for (int pass = 0; pass < 4; ++pass) {
    int c = pass * 256 + tid;
    int r = c >> 4, cc = (c & 15) << 2;
    float4 vv = *(const float4*)(W + (size_t)(kt * 64 + r) * 2048 + nt * 64 + cc);
    u16x4 o;
    o[0] = f2bf(vv.x); o[1] = f2bf(vv.y); o[2] = f2bf(vv.z); o[3] = f2bf(vv.w);
    *(u16x4*)&t[r][cc] = o;
  }
  __syncthreads();
#pragma unroll
  for (int pass = 0; pass < 2; ++pass) {
    int c = pass * 256 + tid;
    int rn = c >> 3, cs = (c & 7) << 3;
    u16x8 o;
#pragma unroll
    for (int j = 0; j < 8; ++j) o[j] = t[cs + j][rn];
    *(u16x8*)(WT + (size_t)(nt * 64 + rn) * 2048 + kt * 64 + cs) = o;
  }
}

// ---------------------------------------------------------------------------
__global__ __launch_bounds__(256) void k_bias_cat(
    const float* __restrict__ bq, const float* __restrict__ bk,
    const float* __restrict__ bv, const float* __restrict__ bg, float* __restrict__ o)
{
  const int i = blockIdx.x * 256 + threadIdx.x;  // 8192
  const int blk = i >> 11;
  const float* s = (blk == 0) ? bq : (blk == 1) ? bk : (blk == 2) ? bv : bg;
  o[i] = s[i & 2047];
}

__global__ __launch_bounds__(256) void k_kv_reduce(const float* __restrict__ part, u16* __restrict__ kvT)
{
  const int i = blockIdx.x * 256 + threadIdx.x;  // 1,048,576
  float s = 0.f;
#pragma unroll
  for (int sp = 0; sp < 8; ++sp) s += part[(size_t)sp * 1048576 + i];
  kvT[i] = f2bf(s);
}

// ---------------------------------------------------------------------------
extern "C" void kernel_launch(void* const* d_in, const int* in_sizes, int n_in,
                              void* d_out, int out_size, void* d_ws, size_t ws_size,
                              hipStream_t stream)
{
  const float* x  = (const float*)d_in[0];
  const float* Wq = (const float*)d_in[1];
  const float* bq = (const float*)d_in[2];
  const float* Wk = (const float*)d_in[3];
  const float* bk = (const float*)d_in[4];
  const float* Wv = (const float*)d_in[5];
  const float* bv = (const float*)d_in[6];
  const float* Wg = (const float*)d_in[7];
  const float* bg = (const float*)d_in[8];
  const float* Wo = (const float*)d_in[9];
  const float* bo = (const float*)d_in[10];
  float* out = (float*)d_out;

  char* ws = (char*)d_ws;
  u16*   xb   = (u16*)(ws + 0x00000000ULL);  // 64MB
  u16*   WT   = (u16*)(ws + 0x04000000ULL);  // 32MB  [Wq|Wk|Wv|Wg]^T bf16
  u16*   WoT  = (u16*)(ws + 0x06000000ULL);  // 8MB
  float* bias = (float*)(ws + 0x06800000ULL);// 32KB
  u16*   q    = (u16*)(ws + 0x06900000ULL);  // 64MB
  u16*   kT   = (u16*)(ws + 0x0A900000ULL);  // 64MB  [bh][d][s]
  u16*   vT   = (u16*)(ws + 0x0E900000ULL);  // 64MB  [bh][d][s]
  u16*   gg   = (u16*)(ws + 0x12900000ULL);  // 64MB
  u16*   kvT  = (u16*)(ws + 0x16900000ULL);  // 2MB
  // aliases (producer/consumer disjoint across sequential launches)
  float* part = (float*)WT;   // WT dead after qkvg (exactly 32MB)
  u16*   attn = xb;           // xb dead after qkvg

  if (ws_size < 0x16B00000ULL) return;

  k_cvt_x<<<16384, 256, 0, stream>>>(x, xb);
  k_cvt_w_t<<<dim3(32, 32), 256, 0, stream>>>(Wq, WT);
  k_cvt_w_t<<<dim3(32, 32), 256, 0, stream>>>(Wk, WT + (size_t)2048 * 2048);
  k_cvt_w_t<<<dim3(32, 32), 256, 0, stream>>>(Wv, WT + (size_t)2 * 2048 * 2048);
  k_cvt_w_t<<<dim3(32, 32), 256, 0, stream>>>(Wg, WT + (size_t)3 * 2048 * 2048);
  k_cvt_w_t<<<dim3(32, 32), 256, 0, stream>>>(Wo, WoT);
  k_bias_cat<<<32, 256, 0, stream>>>(bq, bk, bv, bg, bias);

  k_gemm_qkvg<<<2048, 512, 0, stream>>>(xb, WT, bias, q, kT, vT, gg);

  k_gemm_kv<<<dim3(64, 8), 256, 0, stream>>>(vT, kT, part);
  k_kv_reduce<<<4096, 256, 0, stream>>>(part, kvT);

  k_gemm_attn<<<dim3(32, 64), 256, 0, stream>>>(q, kvT, gg, attn);
  k_gemm_out<<<512, 512, 0, stream>>>(attn, WoT, bo, out);
}